// Round 1
// baseline (441.345 us; speedup 1.0000x reference)
//
#include <hip/hip_runtime.h>

#define TDIM 512
#define FDIM 1024
#define DDIM 128

__device__ __forceinline__ float sigm(float x)  { return 1.0f / (1.0f + __expf(-x)); }
__device__ __forceinline__ float tanh_f(float x){ return 1.0f - 2.0f / (__expf(2.0f * x) + 1.0f); }

// ---------------------------------------------------------------------------
// Kernel 0: transpose emb_w1/emb_w2 (128x128) so lane=d' global reads coalesce.
__global__ __launch_bounds__(256) void transpose_k(const float* __restrict__ w1,
                                                   const float* __restrict__ w2,
                                                   float* __restrict__ w1t,
                                                   float* __restrict__ w2t) {
    int idx = blockIdx.x * 256 + threadIdx.x;   // 0..32767
    int sel = idx >> 14;
    int within = idx & 16383;
    int k = within >> 7, d = within & 127;
    if (sel == 0) w1t[within] = w1[d * 128 + k];
    else          w2t[within] = w2[d * 128 + k];
}

// ---------------------------------------------------------------------------
// Kernel 1 (fused): fc1 GEMM (64x128 tile, K=1024) -> biLSTM(H=1) -> y ->
// e1 = leaky(y @ w1^T + b1) summed over the block's 64 t-rows -> partials.
// Block: 256 threads, rows = 64 consecutive t of one b. Grid: 512 (= 2/CU).
__global__ __launch_bounds__(256) void fused_k(
    const float* __restrict__ x,
    const float* __restrict__ fc1_w, const float* __restrict__ fc1_b,
    const float* __restrict__ wih_f, const float* __restrict__ whh_f,
    const float* __restrict__ bih_f, const float* __restrict__ bhh_f,
    const float* __restrict__ wih_b, const float* __restrict__ whh_b,
    const float* __restrict__ bih_b, const float* __restrict__ bhh_b,
    const float* __restrict__ lout_w, const float* __restrict__ lout_b,
    const float* __restrict__ w1t, const float* __restrict__ emb_b1,
    float* __restrict__ partials)
{
    // 64 KB total LDS -> 2 blocks/CU on 160 KB.
    __shared__ float h_lds[64 * 128];   // fc1 output tile, XOR-swizzled cols
    __shared__ float sbuf[64 * 128];    // GEMM staging (A:32x68, W:32x132) then y (swizzled)

    int tid = threadIdx.x;
    int blk = blockIdx.x;
    int b  = blk >> 3;
    int t0 = (blk & 7) * 64;
    const float* xb = x + (size_t)b * (FDIM * TDIM) + t0;   // x[b,0,f,t0+tt] = xb[f*512+tt]

    float* A = sbuf;            // [32][68]  (pad 68: 16B-aligned rows, conflict-free)
    float* W = sbuf + 32 * 68;  // [32][132] (pad 132: 16B-aligned rows)

    float acc[4][8];
#pragma unroll
    for (int j = 0; j < 4; ++j)
#pragma unroll
        for (int i = 0; i < 8; ++i) acc[j][i] = 0.f;

    int ty = tid >> 4;   // 0..15 -> rows 4*ty..4*ty+3
    int tx = tid & 15;   // 0..15 -> cols 8*tx..8*tx+7

    for (int k0 = 0; k0 < FDIM; k0 += 32) {
        // A tile: 32k x 64t, float4 loads (t contiguous in x) -> coalesced
#pragma unroll
        for (int i = 0; i < 2; ++i) {
            int vid = i * 256 + tid;          // 0..511
            int kk = vid >> 4;                // 0..31
            int tt = (vid & 15) * 4;          // 0..60
            float4 v = *reinterpret_cast<const float4*>(&xb[(size_t)(k0 + kk) * TDIM + tt]);
            *reinterpret_cast<float4*>(&A[kk * 68 + tt]) = v;
        }
        // W tile: 32k x 128d, scalar loads (128B segments per d-row)
#pragma unroll
        for (int i = 0; i < 16; ++i) {
            int vid = i * 256 + tid;          // 0..4095
            int dd = vid >> 5;                // 0..127
            int kk = vid & 31;
            W[kk * 132 + dd] = fc1_w[(size_t)dd * FDIM + k0 + kk];
        }
        __syncthreads();
#pragma unroll
        for (int kk = 0; kk < 32; ++kk) {
            float4 av = *reinterpret_cast<const float4*>(&A[kk * 68 + ty * 4]);
            float4 b0 = *reinterpret_cast<const float4*>(&W[kk * 132 + tx * 8]);
            float4 b1 = *reinterpret_cast<const float4*>(&W[kk * 132 + tx * 8 + 4]);
            float aa[4] = {av.x, av.y, av.z, av.w};
            float bb[8] = {b0.x, b0.y, b0.z, b0.w, b1.x, b1.y, b1.z, b1.w};
#pragma unroll
            for (int j = 0; j < 4; ++j)
#pragma unroll
                for (int i = 0; i < 8; ++i) acc[j][i] = fmaf(aa[j], bb[i], acc[j][i]);
        }
        __syncthreads();
    }

    // Epilogue: h tile -> LDS (swizzled: col' = d ^ ((row&7)<<2) keeps strided
    // LSTM access conflict-free while preserving float4 contiguity).
#pragma unroll
    for (int j = 0; j < 4; ++j) {
        int r = ty * 4 + j;
        int sw = (r & 7) << 2;
#pragma unroll
        for (int i = 0; i < 8; ++i) {
            int d = tx * 8 + i;
            h_lds[r * 128 + (d ^ sw)] = acc[j][i] + fc1_b[d];
        }
    }

    // y init (sbuf reused; A/W dead after final barrier of K-loop)
    float lb = lout_b[0];
    float* y = sbuf;
    for (int i = tid; i < 64 * 128; i += 256) y[i] = lb;
    __syncthreads();

    // ----- biLSTM: thread = (row, dir); 128 serial steps; H = 1 -----
    if (tid < 128) {
        int row = tid >> 1, dir = tid & 1;
        int sw = (row & 7) << 2;
        const float* wih = dir ? wih_b : wih_f;
        const float* whh = dir ? whh_b : whh_f;
        const float* bi  = dir ? bih_b : bih_f;
        const float* bh  = dir ? bhh_b : bhh_f;
        float wi0 = wih[0], wi1 = wih[1], wi2 = wih[2], wi3 = wih[3];
        float wh0 = whh[0], wh1 = whh[1], wh2 = whh[2], wh3 = whh[3];
        float c0 = bi[0] + bh[0], c1 = bi[1] + bh[1], c2 = bi[2] + bh[2], c3 = bi[3] + bh[3];
        float wsel = lout_w[dir];
        float hh = 0.f, cc = 0.f;
        for (int s = 0; s < 128; ++s) {
            int d = dir ? (127 - s) : s;
            float xv = h_lds[row * 128 + (d ^ sw)];
            float gi = fmaf(wi0, xv, fmaf(wh0, hh, c0));
            float gf = fmaf(wi1, xv, fmaf(wh1, hh, c1));
            float gg = fmaf(wi2, xv, fmaf(wh2, hh, c2));
            float go = fmaf(wi3, xv, fmaf(wh3, hh, c3));
            cc = sigm(gf) * cc + sigm(gi) * tanh_f(gg);
            hh = sigm(go) * tanh_f(cc);
            // fwd writes d=s, bwd writes d=127-s: never equal, same-wave lockstep -> race-free
            y[row * 128 + (d ^ sw)] += wsel * hh;
        }
    }
    __syncthreads();

    // ----- emb1 + leaky + sum over rows: thread = (d1, half); 32 rows each -----
    int d1 = tid & 127;
    int half = tid >> 7;
    int r0 = half * 32;
    float accv[32];
#pragma unroll
    for (int j = 0; j < 32; ++j) accv[j] = 0.f;
    for (int k4 = 0; k4 < 128; k4 += 4) {
        float w0v = w1t[(k4 + 0) * 128 + d1];   // coalesced (lane = d1)
        float w1v = w1t[(k4 + 1) * 128 + d1];
        float w2v = w1t[(k4 + 2) * 128 + d1];
        float w3v = w1t[(k4 + 3) * 128 + d1];
#pragma unroll
        for (int j = 0; j < 32; ++j) {
            int r = r0 + j;
            int sw = (r & 7) << 2;
            float4 yv = *reinterpret_cast<const float4*>(&y[r * 128 + (k4 ^ sw)]); // broadcast
            accv[j] = fmaf(yv.x, w0v, accv[j]);
            accv[j] = fmaf(yv.y, w1v, accv[j]);
            accv[j] = fmaf(yv.z, w2v, accv[j]);
            accv[j] = fmaf(yv.w, w3v, accv[j]);
        }
    }
    float b1e = emb_b1[d1];
    float ssum = 0.f;
#pragma unroll
    for (int j = 0; j < 32; ++j) {
        float e = accv[j] + b1e;
        ssum += (e >= 0.f) ? e : 0.2f * e;
    }
    // combine halves via h_lds (free now; post-LSTM barrier already passed)
    h_lds[half * 128 + d1] = ssum;
    __syncthreads();
    if (tid < 128)
        partials[(size_t)blk * 128 + tid] = h_lds[tid] + h_lds[128 + tid];
}

// ---------------------------------------------------------------------------
// Kernel 2: per-batch reduce of 8 partials, /T, then @ emb_w2^T + b2.
__global__ __launch_bounds__(128) void final_k(const float* __restrict__ partials,
                                               const float* __restrict__ w2t,
                                               const float* __restrict__ emb_b2,
                                               float* __restrict__ out) {
    __shared__ float S[128];
    int b = blockIdx.x, tid = threadIdx.x;
    float s = 0.f;
#pragma unroll
    for (int p = 0; p < 8; ++p) s += partials[(size_t)(b * 8 + p) * 128 + tid];
    S[tid] = s * (1.0f / 512.0f);
    __syncthreads();
    float acc = emb_b2[tid];
    for (int k = 0; k < 128; ++k) acc = fmaf(S[k], w2t[k * 128 + tid], acc);
    out[b * 128 + tid] = acc;
}

// ---------------------------------------------------------------------------
extern "C" void kernel_launch(void* const* d_in, const int* in_sizes, int n_in,
                              void* d_out, int out_size, void* d_ws, size_t ws_size,
                              hipStream_t stream) {
    const float* x      = (const float*)d_in[0];
    const float* fc1_w  = (const float*)d_in[1];
    const float* fc1_b  = (const float*)d_in[2];
    const float* wih_f  = (const float*)d_in[3];
    const float* whh_f  = (const float*)d_in[4];
    const float* bih_f  = (const float*)d_in[5];
    const float* bhh_f  = (const float*)d_in[6];
    const float* wih_b  = (const float*)d_in[7];
    const float* whh_b  = (const float*)d_in[8];
    const float* bih_b  = (const float*)d_in[9];
    const float* bhh_b  = (const float*)d_in[10];
    const float* lout_w = (const float*)d_in[11];
    const float* lout_b = (const float*)d_in[12];
    const float* emb_w1 = (const float*)d_in[13];
    const float* emb_b1 = (const float*)d_in[14];
    const float* emb_w2 = (const float*)d_in[15];
    const float* emb_b2 = (const float*)d_in[16];
    float* out = (float*)d_out;

    float* partials = (float*)d_ws;            // 512*128 = 65536 floats
    float* w1t = partials + 512 * 128;         // 16384 floats
    float* w2t = w1t + 16384;                  // 16384 floats

    transpose_k<<<128, 256, 0, stream>>>(emb_w1, emb_w2, w1t, w2t);
    fused_k<<<512, 256, 0, stream>>>(x, fc1_w, fc1_b,
                                     wih_f, whh_f, bih_f, bhh_f,
                                     wih_b, whh_b, bih_b, bhh_b,
                                     lout_w, lout_b, w1t, emb_b1, partials);
    final_k<<<64, 128, 0, stream>>>(partials, w2t, emb_b2, out);
}

// Round 2
// 322.807 us; speedup vs baseline: 1.3672x; 1.3672x over previous
//
#include <hip/hip_runtime.h>
#include <hip/hip_bf16.h>

typedef __attribute__((ext_vector_type(8))) short short8;
typedef __attribute__((ext_vector_type(4))) float f32x4;

#define TDIM 512
#define FDIM 1024

__device__ __forceinline__ float sigm(float x)  { return 1.0f / (1.0f + __expf(-x)); }
__device__ __forceinline__ float tanh_f(float x){ return 1.0f - 2.0f / (__expf(2.0f * x) + 1.0f); }

// ---------------------------------------------------------------------------
// prep: blocks 0..127 transpose emb_w1/emb_w2 -> w1t,w2t ;
//       blocks 128..255 convert fc1_w fp32 -> bf16 (same [d][f] layout).
__global__ __launch_bounds__(256) void prep_k(const float* __restrict__ w1,
                                              const float* __restrict__ w2,
                                              const float* __restrict__ fc1_w,
                                              float* __restrict__ w1t,
                                              float* __restrict__ w2t,
                                              ushort* __restrict__ wb16) {
    int blk = blockIdx.x;
    int tid = threadIdx.x;
    if (blk < 128) {
        int idx = blk * 256 + tid;     // 0..32767
        int sel = idx >> 14;
        int within = idx & 16383;
        int k = within >> 7, d = within & 127;
        if (sel == 0) w1t[within] = w1[d * 128 + k];
        else          w2t[within] = w2[d * 128 + k];
    } else {
        int idx = (blk - 128) * 256 + tid;   // 0..32767, float4 each
        float4 v = reinterpret_cast<const float4*>(fc1_w)[idx];
        ushort4 o;
        o.x = __bfloat16_as_ushort(__float2bfloat16(v.x));
        o.y = __bfloat16_as_ushort(__float2bfloat16(v.y));
        o.z = __bfloat16_as_ushort(__float2bfloat16(v.z));
        o.w = __bfloat16_as_ushort(__float2bfloat16(v.w));
        reinterpret_cast<ushort4*>(wb16)[idx] = o;
    }
}

// ---------------------------------------------------------------------------
// fused: MFMA fc1 (32t x 128d tile, K=1024, no LDS in K-loop) -> biLSTM(H=1)
//        -> y -> e1 = leaky(y @ w1^T + b1) summed over rows -> partials.
// Block: 256 threads = 4 waves in 2x2 (wave tile 16t x 64d). Grid: 1024.
__global__ __launch_bounds__(256, 4) void fused_k(
    const float* __restrict__ x,
    const ushort* __restrict__ wb16, const float* __restrict__ fc1_b,
    const float* __restrict__ wih_f, const float* __restrict__ whh_f,
    const float* __restrict__ bih_f, const float* __restrict__ bhh_f,
    const float* __restrict__ wih_b, const float* __restrict__ whh_b,
    const float* __restrict__ bih_b, const float* __restrict__ bhh_b,
    const float* __restrict__ lout_w, const float* __restrict__ lout_b,
    const float* __restrict__ w1t, const float* __restrict__ emb_b1,
    float* __restrict__ partials)
{
    __shared__ float h_lds[32 * 128];   // fc1 out tile (XOR-swizzled cols)
    __shared__ float y[32 * 128];       // lstm-projected tile (same swizzle)

    int tid = threadIdx.x;
    int blk = blockIdx.x;
    int b  = blk >> 4;
    int t0 = (blk & 15) * 32;

    int lane = tid & 63;
    int wid  = tid >> 6;
    int wr = wid >> 1, wc = wid & 1;
    int l15 = lane & 15, g = lane >> 4;      // g = k-group (0..3)

    // A: x[b, f, t] -> lane reads t = t0+16*wr+l15, f = k0 + 8g + j (stride-512 scalar,
    //    lanes 0..15 give 64B-coalesced segments). Convert fp32->bf16 in-register.
    const float*  xl = x + (size_t)b * (FDIM * TDIM) + (t0 + wr * 16 + l15);
    // B: wb16[d][f], d = 64*wc + 16*ni + l15, f = k0 + 8g + j : 16B vector loads.
    const ushort* wl = wb16 + (size_t)(wc * 64 + l15) * FDIM + g * 8;

    f32x4 acc[4] = {f32x4{0,0,0,0}, f32x4{0,0,0,0}, f32x4{0,0,0,0}, f32x4{0,0,0,0}};

#pragma unroll 2
    for (int k0 = 0; k0 < FDIM; k0 += 32) {
        float av[8];
#pragma unroll
        for (int j = 0; j < 8; ++j)
            av[j] = xl[(size_t)(k0 + g * 8 + j) * TDIM];
        short8 a;
#pragma unroll
        for (int j = 0; j < 8; ++j)
            a[j] = (short)__bfloat16_as_ushort(__float2bfloat16(av[j]));
#pragma unroll
        for (int ni = 0; ni < 4; ++ni) {
            short8 bfr = *reinterpret_cast<const short8*>(wl + k0 + ni * 16 * FDIM);
            acc[ni] = __builtin_amdgcn_mfma_f32_16x16x32_bf16(a, bfr, acc[ni], 0, 0, 0);
        }
    }

    // Epilogue: C/D layout col=lane&15, row=(lane>>4)*4+reg (m89-verified).
#pragma unroll
    for (int ni = 0; ni < 4; ++ni) {
        int col = wc * 64 + ni * 16 + l15;
        float bias = fc1_b[col];
#pragma unroll
        for (int r = 0; r < 4; ++r) {
            int row = wr * 16 + g * 4 + r;
            h_lds[row * 128 + (col ^ ((row & 7) << 2))] = acc[ni][r] + bias;
        }
    }

    // y init
    float lb = lout_b[0];
    for (int i = tid; i < 32 * 128; i += 256) y[i] = lb;
    __syncthreads();

    // ----- biLSTM: thread = (row, dir); 128 serial steps; H = 1 -----
    if (tid < 64) {
        int row = tid >> 1, dir = tid & 1;
        int sw = (row & 7) << 2;
        const float* wih = dir ? wih_b : wih_f;
        const float* whh = dir ? whh_b : whh_f;
        const float* bi  = dir ? bih_b : bih_f;
        const float* bh  = dir ? bhh_b : bhh_f;
        float wi0 = wih[0], wi1 = wih[1], wi2 = wih[2], wi3 = wih[3];
        float wh0 = whh[0], wh1 = whh[1], wh2 = whh[2], wh3 = whh[3];
        float c0 = bi[0] + bh[0], c1 = bi[1] + bh[1], c2 = bi[2] + bh[2], c3 = bi[3] + bh[3];
        float wsel = lout_w[dir];
        float hh = 0.f, cc = 0.f;
        for (int s = 0; s < 128; ++s) {
            int d = dir ? (127 - s) : s;
            float xv = h_lds[row * 128 + (d ^ sw)];
            float gi = fmaf(wi0, xv, fmaf(wh0, hh, c0));
            float gf = fmaf(wi1, xv, fmaf(wh1, hh, c1));
            float gg = fmaf(wi2, xv, fmaf(wh2, hh, c2));
            float go = fmaf(wi3, xv, fmaf(wh3, hh, c3));
            cc = sigm(gf) * cc + sigm(gi) * tanh_f(gg);
            hh = sigm(go) * tanh_f(cc);
            // fwd writes d=s, bwd writes 127-s: distinct, lockstep -> race-free
            y[row * 128 + (d ^ sw)] += wsel * hh;
        }
    }
    __syncthreads();

    // ----- emb1 + leaky + row-sum: thread = (d1, half); 16 rows each -----
    int d1 = tid & 127;
    int half = tid >> 7;
    int r0 = half * 16;
    float accv[16];
#pragma unroll
    for (int j = 0; j < 16; ++j) accv[j] = 0.f;
    for (int k4 = 0; k4 < 128; k4 += 4) {
        float w0v = w1t[(k4 + 0) * 128 + d1];   // coalesced, L2-resident
        float w1v = w1t[(k4 + 1) * 128 + d1];
        float w2v = w1t[(k4 + 2) * 128 + d1];
        float w3v = w1t[(k4 + 3) * 128 + d1];
#pragma unroll
        for (int j = 0; j < 16; ++j) {
            int r = r0 + j;
            int sw = (r & 7) << 2;
            float4 yv = *reinterpret_cast<const float4*>(&y[r * 128 + (k4 ^ sw)]); // broadcast
            accv[j] = fmaf(yv.x, w0v, accv[j]);
            accv[j] = fmaf(yv.y, w1v, accv[j]);
            accv[j] = fmaf(yv.z, w2v, accv[j]);
            accv[j] = fmaf(yv.w, w3v, accv[j]);
        }
    }
    float b1e = emb_b1[d1];
    float ssum = 0.f;
#pragma unroll
    for (int j = 0; j < 16; ++j) {
        float e = accv[j] + b1e;
        ssum += (e >= 0.f) ? e : 0.2f * e;
    }
    h_lds[half * 128 + d1] = ssum;   // h_lds free after LSTM barrier
    __syncthreads();
    if (tid < 128)
        partials[(size_t)blk * 128 + tid] = h_lds[tid] + h_lds[128 + tid];
}

// ---------------------------------------------------------------------------
// final: per-batch reduce of 16 partials, /T, then @ emb_w2^T + b2.
__global__ __launch_bounds__(128) void final_k(const float* __restrict__ partials,
                                               const float* __restrict__ w2t,
                                               const float* __restrict__ emb_b2,
                                               float* __restrict__ out) {
    __shared__ float S[128];
    int b = blockIdx.x, tid = threadIdx.x;
    float s = 0.f;
#pragma unroll
    for (int p = 0; p < 16; ++p) s += partials[(size_t)(b * 16 + p) * 128 + tid];
    S[tid] = s * (1.0f / 512.0f);
    __syncthreads();
    float acc = emb_b2[tid];
    for (int k = 0; k < 128; ++k) acc = fmaf(S[k], w2t[k * 128 + tid], acc);
    out[b * 128 + tid] = acc;
}

// ---------------------------------------------------------------------------
extern "C" void kernel_launch(void* const* d_in, const int* in_sizes, int n_in,
                              void* d_out, int out_size, void* d_ws, size_t ws_size,
                              hipStream_t stream) {
    const float* x      = (const float*)d_in[0];
    const float* fc1_w  = (const float*)d_in[1];
    const float* fc1_b  = (const float*)d_in[2];
    const float* wih_f  = (const float*)d_in[3];
    const float* whh_f  = (const float*)d_in[4];
    const float* bih_f  = (const float*)d_in[5];
    const float* bhh_f  = (const float*)d_in[6];
    const float* wih_b  = (const float*)d_in[7];
    const float* whh_b  = (const float*)d_in[8];
    const float* bih_b  = (const float*)d_in[9];
    const float* bhh_b  = (const float*)d_in[10];
    const float* lout_w = (const float*)d_in[11];
    const float* lout_b = (const float*)d_in[12];
    const float* emb_w1 = (const float*)d_in[13];
    const float* emb_b1 = (const float*)d_in[14];
    const float* emb_w2 = (const float*)d_in[15];
    const float* emb_b2 = (const float*)d_in[16];
    float* out = (float*)d_out;

    float* partials = (float*)d_ws;              // 1024*128 floats = 512 KB
    float* w1t  = partials + 1024 * 128;         // 16384 floats
    float* w2t  = w1t + 16384;                   // 16384 floats
    ushort* wb16 = (ushort*)(w2t + 16384);       // 131072 bf16 = 256 KB

    prep_k<<<256, 256, 0, stream>>>(emb_w1, emb_w2, fc1_w, w1t, w2t, wb16);
    fused_k<<<1024, 256, 0, stream>>>(x, wb16, fc1_b,
                                      wih_f, whh_f, bih_f, bhh_f,
                                      wih_b, whh_b, bih_b, bhh_b,
                                      lout_w, lout_b, w1t, emb_b1, partials);
    final_k<<<64, 128, 0, stream>>>(partials, w2t, emb_b2, out);
}